// Round 1
// baseline (1237.172 us; speedup 1.0000x reference)
//
#include <hip/hip_runtime.h>

#define BATCH 16384
#define DIM 4096
#define NPAIRS 2048
#define G 64

// Each thread handles one float4 of x/out = 2 consecutive pairs.
// Block = 256 threads = 64 q-positions (pair-groups) x 4 batch rows.
// Grid = 16 q-tiles x 4096 b-chunks; tile = bid & 15 so each XCD
// (bid % 8 round-robin) sees only 2 tiles -> 2 MiB of Y in its L2.
__global__ __launch_bounds__(256) void pair_bilinear_kernel(
    const float* __restrict__ x,
    const float* __restrict__ Y,
    float* __restrict__ out)
{
    const int bid    = blockIdx.x;
    const int tile   = bid & 15;        // 0..15
    const int chunk  = bid >> 4;        // 0..4095
    const int lane_q = threadIdx.x & 63;
    const int sub_b  = threadIdx.x >> 6; // 0..3

    const int q = tile * 64 + lane_q;   // 0..1023 (group of 2 pairs)
    const int b = chunk * 4 + sub_b;    // 0..16383

    const size_t row_off = (size_t)b * DIM + (size_t)q * 4;
    const float4 xv = *reinterpret_cast<const float4*>(x + row_off);

    float o[4];
    #pragma unroll
    for (int k = 0; k < 2; ++k) {
        const float uu = (k == 0) ? xv.x : xv.z;
        const float vv = (k == 0) ? xv.y : xv.w;
        const int p = q * 2 + k;

        const float u = fminf(fmaxf(uu, 0.0f), 1.0f) * (float)(G - 1);
        const float v = fminf(fmaxf(vv, 0.0f), 1.0f) * (float)(G - 1);
        int i0 = (int)floorf(u);
        int j0 = (int)floorf(v);
        i0 = min(max(i0, 0), G - 2);
        j0 = min(max(j0, 0), G - 2);
        const float fu = u - (float)i0;
        const float fv = v - (float)j0;

        const float* Yp = Y + (size_t)p * (2 * G * G) + i0 * G + j0;
        #pragma unroll
        for (int c = 0; c < 2; ++c) {
            const float* Ypc = Yp + c * (G * G);
            const float y00 = Ypc[0];
            const float y01 = Ypc[1];
            const float y10 = Ypc[G];
            const float y11 = Ypc[G + 1];
            // lerp form == reference's 4-weight form (exact up to fp rounding)
            const float top = y00 + fv * (y01 - y00);
            const float bot = y10 + fv * (y11 - y10);
            o[2 * k + c] = top + fu * (bot - top);
        }
    }

    float4 ov;
    ov.x = o[0]; ov.y = o[1]; ov.z = o[2]; ov.w = o[3];
    *reinterpret_cast<float4*>(out + row_off) = ov;
}

extern "C" void kernel_launch(void* const* d_in, const int* in_sizes, int n_in,
                              void* d_out, int out_size, void* d_ws, size_t ws_size,
                              hipStream_t stream) {
    const float* x = (const float*)d_in[0];
    const float* Y = (const float*)d_in[1];
    float* out     = (float*)d_out;

    // 16 tiles * (BATCH/4) chunks = 65536 blocks of 256 threads
    const int n_blocks = 16 * (BATCH / 4);
    pair_bilinear_kernel<<<n_blocks, 256, 0, stream>>>(x, Y, out);
}

// Round 3
// 624.234 us; speedup vs baseline: 1.9819x; 1.9819x over previous
//
#include <hip/hip_runtime.h>

#define BATCH 16384
#define DIM 4096
#define NPAIRS 2048
#define G 64

typedef float f32x4 __attribute__((ext_vector_type(4)));

// Thread = one float4 of x/out = 2 consecutive pairs.
// Block = 256 threads = 32 q-groups (128 floats contiguous) x 8 batch rows.
// Grid = 32 tiles (slowest) x 2048 batch-chunks (fastest).
// All ~2048 in-flight blocks share ONE tile -> active Y slice = 32 q-groups
// * 64 KiB = 2 MiB, L2-resident on every XCD; Y streams from HBM once.
// x/out use non-temporal accesses so streaming traffic doesn't evict Y.
__global__ __launch_bounds__(256) void pair_bilinear_kernel(
    const float* __restrict__ x,
    const float* __restrict__ Y,
    float* __restrict__ out)
{
    const int bid    = blockIdx.x;
    const int tile   = bid >> 11;        // 0..31  (slowest-varying)
    const int chunk  = bid & 2047;       // 0..2047
    const int lane_q = threadIdx.x & 31; // 0..31
    const int sub_b  = threadIdx.x >> 5; // 0..7

    const int q = tile * 32 + lane_q;    // 0..1023 (group of 2 pairs)
    const int b = chunk * 8 + sub_b;     // 0..16383

    const size_t row_off = (size_t)b * DIM + (size_t)q * 4;
    const f32x4 xv = __builtin_nontemporal_load(
        reinterpret_cast<const f32x4*>(x + row_off));

    float o[4];
    #pragma unroll
    for (int k = 0; k < 2; ++k) {
        const float uu = xv[2 * k];
        const float vv = xv[2 * k + 1];
        const int p = q * 2 + k;

        const float u = fminf(fmaxf(uu, 0.0f), 1.0f) * (float)(G - 1);
        const float v = fminf(fmaxf(vv, 0.0f), 1.0f) * (float)(G - 1);
        int i0 = (int)floorf(u);
        int j0 = (int)floorf(v);
        i0 = min(max(i0, 0), G - 2);
        j0 = min(max(j0, 0), G - 2);
        const float fu = u - (float)i0;
        const float fv = v - (float)j0;

        const float* Yp = Y + (size_t)p * (2 * G * G) + i0 * G + j0;
        #pragma unroll
        for (int c = 0; c < 2; ++c) {
            const float* Ypc = Yp + c * (G * G);
            const float y00 = Ypc[0];
            const float y01 = Ypc[1];
            const float y10 = Ypc[G];
            const float y11 = Ypc[G + 1];
            const float top = y00 + fv * (y01 - y00);
            const float bot = y10 + fv * (y11 - y10);
            o[2 * k + c] = top + fu * (bot - top);
        }
    }

    f32x4 ov;
    ov[0] = o[0]; ov[1] = o[1]; ov[2] = o[2]; ov[3] = o[3];
    __builtin_nontemporal_store(ov, reinterpret_cast<f32x4*>(out + row_off));
}

extern "C" void kernel_launch(void* const* d_in, const int* in_sizes, int n_in,
                              void* d_out, int out_size, void* d_ws, size_t ws_size,
                              hipStream_t stream) {
    const float* x = (const float*)d_in[0];
    const float* Y = (const float*)d_in[1];
    float* out     = (float*)d_out;

    // 32 tiles * 2048 chunks = 65536 blocks of 256 threads
    const int n_blocks = 32 * 2048;
    pair_bilinear_kernel<<<n_blocks, 256, 0, stream>>>(x, Y, out);
}

// Round 5
// 216.398 us; speedup vs baseline: 5.7171x; 2.8847x over previous
//
#include <hip/hip_runtime.h>

#define BATCH 16384
#define DIM 4096
#define G 64
#define PPB 8          // pairs per block
#define THREADS 1024

typedef float f32x4 __attribute__((ext_vector_type(4)));

__device__ __forceinline__ unsigned int bf16_rne(float f) {
    unsigned int u = __builtin_bit_cast(unsigned int, f);
    return (u + 0x7FFFu + ((u >> 16) & 1u)) >> 16;
}

// Block = one pair-group of 8 pairs; their grids staged in 128 KiB static LDS
// as packed bf16 (ch1<<16 | ch0): one ds_read_b32 per corner -> both channels,
// 4B granularity (no L2 line over-fetch).
// Block covers 16 consecutive x/out columns (= 8 pairs); a wave spans 16 rows
// x 64B contiguous -> perfect coalescing. Grid = 256 blocks (1/CU); Y read
// from HBM exactly once.
__global__ __launch_bounds__(THREADS) void pair_bilinear_kernel(
    const float* __restrict__ x,
    const float* __restrict__ Y,
    float* __restrict__ out)
{
    __shared__ unsigned int ylds[PPB * G * G];   // 32768 words = 128 KiB
    const int pg  = blockIdx.x;                  // pair-group 0..255
    const int tid = threadIdx.x;

    // ---- stage: Y[pg*8 .. pg*8+7][2][64][64] f32 -> packed bf16 LDS ----
    const float* Yb = Y + (size_t)pg * (PPB * 2 * G * G);
    #pragma unroll
    for (int it = 0; it < (PPB * G * G) / THREADS; ++it) {
        const int w   = it * THREADS + tid;      // word index 0..32767
        const int pl  = w >> 12;                 // pair-local 0..7
        const int pos = w & 4095;                // node 0..4095
        const float c0 = Yb[pl * 8192 + pos];
        const float c1 = Yb[pl * 8192 + 4096 + pos];
        ylds[w] = bf16_rne(c0) | (bf16_rne(c1) << 16);
    }
    __syncthreads();

    // ---- main: stream rows ----
    const int seg  = tid & 3;                    // which float4 of the 64B
    const int row0 = tid >> 2;                   // 0..255
    const size_t col = (size_t)pg * 16 + seg * 4;   // 16 floats per block!

    size_t off = (size_t)row0 * DIM + col;
    f32x4 xv = __builtin_nontemporal_load(reinterpret_cast<const f32x4*>(x + off));

    const int NITER = BATCH / (THREADS / 4);     // 64
    for (int it = 0; it < NITER; ++it) {
        const size_t off_next = off + (size_t)(THREADS / 4) * DIM;
        f32x4 xn;
        if (it + 1 < NITER)
            xn = __builtin_nontemporal_load(reinterpret_cast<const f32x4*>(x + off_next));

        f32x4 ov;
        #pragma unroll
        for (int k = 0; k < 2; ++k) {
            const float u = fminf(fmaxf(xv[2 * k], 0.0f), 1.0f) * (float)(G - 1);
            const float v = fminf(fmaxf(xv[2 * k + 1], 0.0f), 1.0f) * (float)(G - 1);
            int i0 = min((int)u, G - 2);
            int j0 = min((int)v, G - 2);
            const float fu = u - (float)i0;
            const float fv = v - (float)j0;

            const int a = ((seg * 2 + k) << 12) + i0 * G + j0;
            const unsigned int w00 = ylds[a];
            const unsigned int w01 = ylds[a + 1];
            const unsigned int w10 = ylds[a + G];
            const unsigned int w11 = ylds[a + G + 1];

            // ch0 = low half, ch1 = high half
            const float c000 = __uint_as_float(w00 << 16);
            const float c001 = __uint_as_float(w01 << 16);
            const float c010 = __uint_as_float(w10 << 16);
            const float c011 = __uint_as_float(w11 << 16);
            const float c100 = __uint_as_float(w00 & 0xFFFF0000u);
            const float c101 = __uint_as_float(w01 & 0xFFFF0000u);
            const float c110 = __uint_as_float(w10 & 0xFFFF0000u);
            const float c111 = __uint_as_float(w11 & 0xFFFF0000u);

            const float t0 = c000 + fv * (c001 - c000);
            const float b0 = c010 + fv * (c011 - c010);
            const float t1 = c100 + fv * (c101 - c100);
            const float b1 = c110 + fv * (c111 - c110);
            ov[2 * k]     = t0 + fu * (b0 - t0);
            ov[2 * k + 1] = t1 + fu * (b1 - t1);
        }

        __builtin_nontemporal_store(ov, reinterpret_cast<f32x4*>(out + off));
        off = off_next;
        xv = xn;
    }
}

extern "C" void kernel_launch(void* const* d_in, const int* in_sizes, int n_in,
                              void* d_out, int out_size, void* d_ws, size_t ws_size,
                              hipStream_t stream) {
    const float* x = (const float*)d_in[0];
    const float* Y = (const float*)d_in[1];
    float* out     = (float*)d_out;

    // 2048 pairs / 8 per block = 256 blocks (one per CU)
    pair_bilinear_kernel<<<256, THREADS, 0, stream>>>(x, Y, out);
}